// Round 4
// baseline (255.742 us; speedup 1.0000x reference)
//
#include <hip/hip_runtime.h>
#include <hip/hip_bf16.h>
#include <cstddef>

// Problem constants (must match reference)
#define BN   1024   // B
#define NEGN 5      // NEG
#define NBRN 50     // NBR
#define DN   128    // D
#define EN   4      // E
#define MPAD 64     // padded neighbor-row count for MFMA tiles
#define NEG_INF_F (-4294967295.0f)

typedef __bf16 bf16_t;
typedef __bf16 bf16x8 __attribute__((ext_vector_type(8)));
typedef __bf16 bf16x4 __attribute__((ext_vector_type(4)));
typedef float  f32x4  __attribute__((ext_vector_type(4)));

__device__ __forceinline__ float leaky_f(float x) { return x >= 0.0f ? x : 0.01f * x; }

__device__ __forceinline__ float wave_sum(float v) {
#pragma unroll
    for (int off = 32; off; off >>= 1) v += __shfl_xor(v, off, 64);
    return v;
}
__device__ __forceinline__ float wave_max(float v) {
#pragma unroll
    for (int off = 32; off; off >>= 1) v = fmaxf(v, __shfl_xor(v, off, 64));
    return v;
}
__device__ __forceinline__ float sigmoid_f(float x) {
    if (x >= 0.0f) { float z = __expf(-x); return 1.0f / (1.0f + z); }
    float z = __expf(x); return z / (1.0f + z);
}

// ---------------------------------------------------------------------------
// Kernel 0: prep — WnT_bf16[n][k] = bf16(W_nbr[k][n])
// ---------------------------------------------------------------------------
__global__ __launch_bounds__(256) void prep_kernel(
    const float* __restrict__ Wn, bf16_t* __restrict__ WnT)
{
    const int idx = blockIdx.x * 256 + threadIdx.x;
    if (idx < DN * DN) {
        const int n = idx >> 7, k = idx & 127;
        WnT[idx] = (bf16_t)Wn[k * DN + n];
    }
}

// ---------------------------------------------------------------------------
// Kernel 1: node latents  leaky(emb[id] @ W_node + b_node)  (fp32)
// ---------------------------------------------------------------------------
__global__ __launch_bounds__(128) void latent_kernel(
    const float* __restrict__ emb, const float* __restrict__ W, const float* __restrict__ bias,
    const int* __restrict__ s_ids, const int* __restrict__ t_ids,
    const int* __restrict__ s_negs, const int* __restrict__ t_negs,
    float* __restrict__ sE, float* __restrict__ tE,
    float* __restrict__ negS, float* __restrict__ negT)
{
    const int tid = threadIdx.x;           // 0..127 = output col
    const int r0 = blockIdx.x * 8;
    __shared__ float rows[8][DN];
    __shared__ int ids_l[8];

    if (tid < 8) {
        int r = r0 + tid;
        int id;
        if (r < BN)                       id = s_ids[r];
        else if (r < 2 * BN)              id = t_ids[r - BN];
        else if (r < 2 * BN + BN * NEGN)  id = s_negs[r - 2 * BN];
        else                              id = t_negs[r - 2 * BN - BN * NEGN];
        ids_l[tid] = id;
    }
    __syncthreads();
#pragma unroll
    for (int r8 = 0; r8 < 8; ++r8)
        rows[r8][tid] = emb[(size_t)ids_l[r8] * DN + tid];
    __syncthreads();

    float acc[8];
#pragma unroll
    for (int r8 = 0; r8 < 8; ++r8) acc[r8] = 0.0f;

    for (int i0 = 0; i0 < DN; i0 += 4) {
        const float w0 = W[(i0 + 0) * DN + tid];
        const float w1 = W[(i0 + 1) * DN + tid];
        const float w2 = W[(i0 + 2) * DN + tid];
        const float w3 = W[(i0 + 3) * DN + tid];
#pragma unroll
        for (int r8 = 0; r8 < 8; ++r8) {
            const float4 a = *reinterpret_cast<const float4*>(&rows[r8][i0]);
            acc[r8] = fmaf(a.x, w0, fmaf(a.y, w1, fmaf(a.z, w2, fmaf(a.w, w3, acc[r8]))));
        }
    }
    const float bb = bias[tid];
#pragma unroll
    for (int r8 = 0; r8 < 8; ++r8) {
        const int r = r0 + r8;
        const float v = leaky_f(acc[r8] + bb);
        float* dst;
        if (r < BN)                       dst = sE   + (size_t)r * DN;
        else if (r < 2 * BN)              dst = tE   + (size_t)(r - BN) * DN;
        else if (r < 2 * BN + BN * NEGN)  dst = negS + (size_t)(r - 2 * BN) * DN;
        else                              dst = negT + (size_t)(r - 2 * BN - BN * NEGN) * DN;
        dst[tid] = v;
    }
}

// ---------------------------------------------------------------------------
// Kernel 2: per (side,b) block handling ALL 4 edge types.
//   phase0: VT(16 rows: npe_0..3,tgt,neg0..4,Wa,zeros) + exact fp32 norms
//           + ids/mask/weights for all 4 e  (amortized 4x)
//   per e:  [issue gather(e+1)->regs] GEMM1 MFMA (L=leaky(Eg@Wn+bn), B from
//           global WnT) -> epilogue (n2, L->LDS) -> GEMM2 MFMA (dots->dotL[e])
//           -> barrier -> write staged regs -> barrier      (T14 overlap)
//   finale: 4 waves in parallel, wave w = softmax/pos/neg/hete for e=w
// grid = 2*B = 2048 blocks x 256 thr.  LDS ~36KB -> 4 blocks/CU.
// ---------------------------------------------------------------------------
__global__ __launch_bounds__(256, 4) void edge_kernel(
    const float* __restrict__ emb, const float* __restrict__ ete,
    const bf16_t* __restrict__ WnT, const float* __restrict__ bn,
    const float* __restrict__ Wa, const float* __restrict__ ba,
    const int* __restrict__ s_nbr_ids, const int* __restrict__ s_nbr_masks, const float* __restrict__ s_nbr_w,
    const int* __restrict__ t_nbr_ids, const int* __restrict__ t_nbr_masks, const float* __restrict__ t_nbr_w,
    const float* __restrict__ sE, const float* __restrict__ tE,
    const float* __restrict__ negS, const float* __restrict__ negT,
    float* __restrict__ posW, float* __restrict__ heteW, float* __restrict__ negW)
{
    const int bid  = blockIdx.x;
    const int b    = bid & (BN - 1);
    const int side = bid >> 10;

    const int*   ids_p;  const int* mask_p; const float* w_p;
    const float* node_p; const float* tgt_p; const float* negs_p;
    if (side == 0) { ids_p = s_nbr_ids; mask_p = s_nbr_masks; w_p = s_nbr_w;
                     node_p = sE; tgt_p = tE; negs_p = negT; }
    else           { ids_p = t_nbr_ids; mask_p = t_nbr_masks; w_p = t_nbr_w;
                     node_p = tE; tgt_p = sE; negs_p = negS; }

    // LDS (~36.2 KB): swizzle = element-index XOR (col ^ ((row&7)<<3)) per row
    __shared__ __align__(16) bf16_t buf[MPAD * DN];   // 16 KB: Eg rows, then L (in place)
    __shared__ __align__(16) bf16_t VT[16 * DN];      // 4 KB
    __shared__ float dotL[EN][MPAD][12];              // 12 KB (cols 0..10 used)
    __shared__ float n2_l[EN][MPAD];                  // 1 KB
    __shared__ float norm_l[10];
    __shared__ int   ids_l[EN * NBRN];
    __shared__ int   mk_l[EN * NBRN];
    __shared__ float w_l[EN * NBRN];

    const int tid  = threadIdx.x;
    const int lane = tid & 63;
    const int w    = tid >> 6;       // wave id 0..3
    const int l15  = lane & 15;
    const int l4   = lane >> 4;

    // ---- phase 0a: ids / masks / weights for all 4 e ----
    for (int idx = tid; idx < EN * NBRN; idx += 256) {
        const int e = idx / NBRN, j = idx - e * NBRN;
        const int src = (e * BN + b) * NBRN + j;
        ids_l[idx] = ids_p[src];
        mk_l[idx]  = mask_p[src];
        w_l[idx]   = w_p[src];
    }

    // ---- phase 0b: VT rows 0..15 + norms 0..9 (exact fp32) ----
#pragma unroll
    for (int it = 0; it < 2; ++it) {
        const int idx = it * 256 + tid;          // 0..511, fully active
        const int q = idx >> 5, c4 = idx & 31;
        const int c = c4 * 4;
        float4 v;
        if (q < 4) {
            const float4 np = *reinterpret_cast<const float4*>(node_p + (size_t)b * DN + c);
            const float4 ep = *reinterpret_cast<const float4*>(ete + q * DN + c);
            v.x = np.x + ep.x; v.y = np.y + ep.y; v.z = np.z + ep.z; v.w = np.w + ep.w;
        } else if (q == 4) {
            v = *reinterpret_cast<const float4*>(tgt_p + (size_t)b * DN + c);
        } else if (q < 10) {
            v = *reinterpret_cast<const float4*>(negs_p + ((size_t)b * NEGN + (q - 5)) * DN + c);
        } else if (q == 10) {
            v = *reinterpret_cast<const float4*>(Wa + c);
        } else {
            v.x = v.y = v.z = v.w = 0.0f;
        }
        float p = v.x * v.x + v.y * v.y + v.z * v.z + v.w * v.w;
#pragma unroll
        for (int off = 1; off <= 16; off <<= 1) p += __shfl_xor(p, off, 64);
        if (c4 == 0 && q < 10) norm_l[q] = p;
        bf16x4 h; h[0]=(bf16_t)v.x; h[1]=(bf16_t)v.y; h[2]=(bf16_t)v.z; h[3]=(bf16_t)v.w;
        *reinterpret_cast<bf16x4*>(&VT[q * DN + (c ^ ((q & 7) << 3))]) = h;
    }

    // ---- phase 0c: zero pad rows 50..63 of buf (once; stale-finite after) ----
    for (int idx = tid; idx < (MPAD - NBRN) * 32; idx += 256) {
        const int j = NBRN + (idx >> 5), c4 = idx & 31;
        bf16x4 z; z[0]=(bf16_t)0.f; z[1]=(bf16_t)0.f; z[2]=(bf16_t)0.f; z[3]=(bf16_t)0.f;
        *reinterpret_cast<bf16x4*>(&buf[j * DN + ((c4 * 4) ^ ((j & 7) << 3))]) = z;
    }
    __syncthreads();

    // ---- stage e=0 directly ----
#pragma unroll
    for (int i = 0; i < 7; ++i) {
        const int flat = i * 256 + tid;
        if (flat < NBRN * 32) {
            const int j = flat >> 5, c4 = flat & 31;
            const float4 f = *reinterpret_cast<const float4*>(
                emb + (size_t)ids_l[j] * DN + c4 * 4);
            bf16x4 h; h[0]=(bf16_t)f.x; h[1]=(bf16_t)f.y; h[2]=(bf16_t)f.z; h[3]=(bf16_t)f.w;
            *reinterpret_cast<bf16x4*>(&buf[j * DN + ((c4 * 4) ^ ((j & 7) << 3))]) = h;
        }
    }
    __syncthreads();

    // ---- main loop over edge types ----
    for (int e = 0; e < EN; ++e) {
        // T14: issue next e's gather into registers (hidden under GEMMs)
        float4 rg[7];
        if (e < EN - 1) {
#pragma unroll
            for (int i = 0; i < 7; ++i) {
                const int flat = i * 256 + tid;
                if (flat < NBRN * 32) {
                    const int j = flat >> 5, c4 = flat & 31;
                    rg[i] = *reinterpret_cast<const float4*>(
                        emb + (size_t)ids_l[(e + 1) * NBRN + j] * DN + c4 * 4);
                }
            }
        }

        // GEMM1: L = leaky(Eg @ Wn + bn); B-frags from global WnT (L1/L2-hot)
        f32x4 accv[8];
#pragma unroll
        for (int nt = 0; nt < 8; ++nt) accv[nt] = (f32x4){0.f, 0.f, 0.f, 0.f};

        const int arow = w * 16 + l15;
#pragma unroll 1
        for (int ks = 0; ks < 4; ++ks) {
            const int k0 = ks * 32 + l4 * 8;
            const bf16x8 a = *reinterpret_cast<const bf16x8*>(
                &buf[arow * DN + (k0 ^ ((arow & 7) << 3))]);
#pragma unroll
            for (int nt = 0; nt < 8; ++nt) {
                const bf16x8 bfr = *reinterpret_cast<const bf16x8*>(
                    WnT + (nt * 16 + l15) * DN + k0);
                accv[nt] = __builtin_amdgcn_mfma_f32_16x16x32_bf16(a, bfr, accv[nt], 0, 0, 0);
            }
        }

        // epilogue: bias+leaky, ||L_j||^2, store L back into buf (own rows only)
        float n2p[4] = {0.f, 0.f, 0.f, 0.f};
#pragma unroll
        for (int nt = 0; nt < 8; ++nt) {
            const int coln = nt * 16 + l15;
            const float bb = bn[coln];
#pragma unroll
            for (int r = 0; r < 4; ++r) {
                float v = leaky_f(accv[nt][r] + bb);
                n2p[r] += v * v;
                const int row = w * 16 + l4 * 4 + r;
                buf[row * DN + (coln ^ ((row & 7) << 3))] = (bf16_t)v;
            }
        }
#pragma unroll
        for (int r = 0; r < 4; ++r) {
            float p = n2p[r];
#pragma unroll
            for (int off = 1; off <= 8; off <<= 1) p += __shfl_xor(p, off, 64);
            if (l15 == 0) n2_l[e][w * 16 + l4 * 4 + r] = p;
        }

        // GEMM2: dots = L @ VT^T  (cols 0..10 useful)
        f32x4 dacc = (f32x4){0.f, 0.f, 0.f, 0.f};
#pragma unroll
        for (int ks = 0; ks < 4; ++ks) {
            const int k0 = ks * 32 + l4 * 8;
            const bf16x8 a   = *reinterpret_cast<const bf16x8*>(
                &buf[arow * DN + (k0 ^ ((arow & 7) << 3))]);
            const bf16x8 bfr = *reinterpret_cast<const bf16x8*>(
                &VT[l15 * DN + (k0 ^ ((l15 & 7) << 3))]);
            dacc = __builtin_amdgcn_mfma_f32_16x16x32_bf16(a, bfr, dacc, 0, 0, 0);
        }
        if (l15 < 11) {
#pragma unroll
            for (int r = 0; r < 4; ++r)
                dotL[e][w * 16 + l4 * 4 + r][l15] = dacc[r];
        }
        __syncthreads();   // all waves done reading buf for this e

        if (e < EN - 1) {
            // write staged rows for e+1
#pragma unroll
            for (int i = 0; i < 7; ++i) {
                const int flat = i * 256 + tid;
                if (flat < NBRN * 32) {
                    const int j = flat >> 5, c4 = flat & 31;
                    bf16x4 h; h[0]=(bf16_t)rg[i].x; h[1]=(bf16_t)rg[i].y;
                              h[2]=(bf16_t)rg[i].z; h[3]=(bf16_t)rg[i].w;
                    *reinterpret_cast<bf16x4*>(&buf[j * DN + ((c4 * 4) ^ ((j & 7) << 3))]) = h;
                }
            }
            __syncthreads();
        }
    }

    // ---- finale: wave w handles e = w ----
    {
        const int e = w;
        const int j = lane;
        const bool act = j < NBRN;
        float mut = 0.0f, wj = 0.0f, hw = 0.0f;
        float mn[NEGN];
#pragma unroll
        for (int n = 0; n < NEGN; ++n) mn[n] = 0.0f;
        int mk = 0;
        float x = NEG_INF_F;
        if (act) {
            const float n2 = n2_l[e][j];
            const float dj = 2.0f * dotL[e][j][e] - norm_l[e] - n2;
            mut            = 2.0f * dotL[e][j][4] - norm_l[4] - n2;
#pragma unroll
            for (int n = 0; n < NEGN; ++n)
                mn[n] = 2.0f * dotL[e][j][5 + n] - norm_l[5 + n] - n2;
            hw = dotL[e][j][10];
            mk = mk_l[e * NBRN + j];
            wj = w_l[e * NBRN + j];
            x = mk ? dj : NEG_INF_F;
        }
        const float m  = wave_max(x);
        const float ex = act ? __expf(x - m) : 0.0f;   // exactly 50 summands
        const float S  = wave_sum(ex);
        const float atts  = ex / S;
        const float atts2 = (act && mk) ? atts : 0.0f;
        const float nw = atts2 * wj;
        const float posv = wave_sum(nw * mut);
        float nsum[NEGN];
#pragma unroll
        for (int n = 0; n < NEGN; ++n) nsum[n] = wave_sum(nw * mn[n]);
        const float wsum = wave_sum(act ? wj : 0.0f);
        const float msum = wave_sum(act ? (float)mk : 0.0f);
        const float hsum = wave_sum(atts2 * hw);       // = avg_embed . Wa
        if (j == 0) {
            const float nbr_n = fminf(fmaxf(msum, 1.0f), (float)NBRN);
            const float ave_w = wsum / nbr_n;
            const int o = (side * EN + e) * BN + b;
            posW[o]  = posv;
            heteW[o] = leaky_f(ave_w * hsum + ba[0]);
#pragma unroll
            for (int n = 0; n < NEGN; ++n) negW[(size_t)o * NEGN + n] = nsum[n];
        }
    }
}

// ---------------------------------------------------------------------------
// Kernel 3: allpos[side][e] = all_b(flags[e][b] > 0)
// ---------------------------------------------------------------------------
__global__ __launch_bounds__(256) void allpos_kernel(
    const int* __restrict__ s_flags, const int* __restrict__ t_flags, int* __restrict__ allpos)
{
    const int side = blockIdx.x >> 2, e = blockIdx.x & 3;
    const int* f = side ? t_flags : s_flags;
    int ok = 1;
    for (int b = threadIdx.x; b < BN; b += 256) ok &= (f[e * BN + b] > 0);
    ok = __syncthreads_and(ok);
    if (threadIdx.x == 0) allpos[blockIdx.x] = ok;
}

// ---------------------------------------------------------------------------
// Kernel 4: per-b loss partial (mu, neg_mus, double-softmax over E, log-sigmoids)
// ---------------------------------------------------------------------------
__global__ __launch_bounds__(64) void loss_kernel(
    const int* __restrict__ e_types, const float* __restrict__ ete,
    const int* __restrict__ s_flags, const int* __restrict__ t_flags,
    const float* __restrict__ sE, const float* __restrict__ tE,
    const float* __restrict__ negS, const float* __restrict__ negT,
    const float* __restrict__ posW, const float* __restrict__ heteW,
    const float* __restrict__ negW, const int* __restrict__ allpos,
    float* __restrict__ partials)
{
    const int b = blockIdx.x;
    const int lane = threadIdx.x;   // 64 lanes, each covers dims lane and lane+64
    const int et = e_types[b];

    const float se0 = sE[(size_t)b * DN + lane],      se1 = sE[(size_t)b * DN + lane + 64];
    const float te0 = tE[(size_t)b * DN + lane],      te1 = tE[(size_t)b * DN + lane + 64];
    const float ee0 = ete[et * DN + lane],            ee1 = ete[et * DN + lane + 64];

    float d0 = se0 + ee0 - te0, d1 = se1 + ee1 - te1;
    const float mu = -wave_sum(d0 * d0 + d1 * d1);

    float nmst[NEGN], nmts[NEGN];
#pragma unroll
    for (int n = 0; n < NEGN; ++n) {
        const float* nt = negT + ((size_t)b * NEGN + n) * DN;
        const float* ns = negS + ((size_t)b * NEGN + n) * DN;
        float a0 = se0 - nt[lane], a1 = se1 - nt[lane + 64];
        nmst[n] = -wave_sum(a0 * a0 + a1 * a1);
        float c0 = te0 - ns[lane], c1 = te1 - ns[lane + 64];
        nmts[n] = -wave_sum(c0 * c0 + c1 * c1);
    }

    if (lane == 0) {
        float posl[2];
        float negl[2][NEGN];
        for (int side = 0; side < 2; ++side) {
            const int* fl = side ? t_flags : s_flags;
            float att[EN], pv[EN];
            int mk[EN], ap[EN];
#pragma unroll
            for (int ei = 0; ei < EN; ++ei) {
                ap[ei] = allpos[side * EN + ei];
                mk[ei] = fl[ei * BN + b] > 0;
                const int o = (side * EN + ei) * BN + b;
                att[ei] = ap[ei] ? 0.0f : heteW[o];
                pv[ei]  = ap[ei] ? 0.0f : posW[o];
            }
            // softmax 1: where(mask, att, NEG_INF)
            float x[EN], m = NEG_INF_F;
#pragma unroll
            for (int ei = 0; ei < EN; ++ei) { x[ei] = mk[ei] ? att[ei] : NEG_INF_F; m = fmaxf(m, x[ei]); }
            float s = 0.0f, ex[EN];
#pragma unroll
            for (int ei = 0; ei < EN; ++ei) { ex[ei] = __expf(x[ei] - m); s += ex[ei]; }
            float v1[EN];
#pragma unroll
            for (int ei = 0; ei < EN; ++ei) v1[ei] = ex[ei] / s;
            // softmax 2: softmax(where(mask, v1, 0.0))  (no output masking!)
            float y[EN], m2 = NEG_INF_F;
#pragma unroll
            for (int ei = 0; ei < EN; ++ei) { y[ei] = mk[ei] ? v1[ei] : 0.0f; m2 = fmaxf(m2, y[ei]); }
            float s2 = 0.0f, ex2[EN];
#pragma unroll
            for (int ei = 0; ei < EN; ++ei) { ex2[ei] = __expf(y[ei] - m2); s2 += ex2[ei]; }
            float pl = 0.0f;
            float nl[NEGN];
#pragma unroll
            for (int n = 0; n < NEGN; ++n) nl[n] = 0.0f;
#pragma unroll
            for (int ei = 0; ei < EN; ++ei) {
                const float na = ex2[ei] / s2;
                pl += na * pv[ei];
                const int o = (side * EN + ei) * BN + b;
#pragma unroll
                for (int n = 0; n < NEGN; ++n) {
                    const float nv = ap[ei] ? 0.0f : negW[(size_t)o * NEGN + n];
                    nl[n] += na * nv;
                }
            }
            posl[side] = pl;
#pragma unroll
            for (int n = 0; n < NEGN; ++n) negl[side][n] = nl[n];
        }

        const float lam = mu + posl[0] + posl[1];
        float total = -logf(sigmoid_f(lam) + 1e-6f) / (float)BN;
#pragma unroll
        for (int n = 0; n < NEGN; ++n) {
            total += -logf(sigmoid_f(-(nmst[n] + negl[0][n])) + 1e-6f) / (float)(BN * NEGN);
            total += -logf(sigmoid_f(-(nmts[n] + negl[1][n])) + 1e-6f) / (float)(BN * NEGN);
        }
        partials[b] = total;
    }
}

// ---------------------------------------------------------------------------
// Kernel 5: reduce partials + NORM_RATE * sum(ete^2) -> d_out[0]
// ---------------------------------------------------------------------------
__global__ __launch_bounds__(256) void final_kernel(
    const float* __restrict__ partials, const float* __restrict__ ete, float* __restrict__ out)
{
    __shared__ float red[256];
    const int tid = threadIdx.x;
    float s = 0.0f;
    for (int i = tid; i < BN; i += 256) s += partials[i];
    float t = 0.0f;
    for (int i = tid; i < EN * DN; i += 256) { const float v = ete[i]; t += v * v; }
    red[tid] = s + 1e-4f * t;
    __syncthreads();
    for (int st = 128; st > 0; st >>= 1) {
        if (tid < st) red[tid] += red[tid + st];
        __syncthreads();
    }
    if (tid == 0) out[0] = red[0];
}

// ---------------------------------------------------------------------------
extern "C" void kernel_launch(void* const* d_in, const int* in_sizes, int n_in,
                              void* d_out, int out_size, void* d_ws, size_t ws_size,
                              hipStream_t stream)
{
    const int*   e_types   = (const int*)  d_in[0];
    const int*   s_ids     = (const int*)  d_in[1];
    // d_in[2] s_types: inert
    const int*   s_negs    = (const int*)  d_in[3];
    const int*   s_nbr_ids = (const int*)  d_in[4];
    const int*   s_nbr_msk = (const int*)  d_in[5];
    const float* s_nbr_w   = (const float*)d_in[6];
    const int*   s_flags   = (const int*)  d_in[7];
    const int*   t_ids     = (const int*)  d_in[8];
    // d_in[9] t_types: inert
    const int*   t_negs    = (const int*)  d_in[10];
    const int*   t_nbr_ids = (const int*)  d_in[11];
    const int*   t_nbr_msk = (const int*)  d_in[12];
    const float* t_nbr_w   = (const float*)d_in[13];
    const int*   t_flags   = (const int*)  d_in[14];
    const float* emb       = (const float*)d_in[15];
    const float* ete       = (const float*)d_in[16];
    const float* W_node    = (const float*)d_in[17];
    const float* b_node    = (const float*)d_in[18];
    const float* W_nbr     = (const float*)d_in[19];
    const float* b_nbr     = (const float*)d_in[20];
    const float* W_att     = (const float*)d_in[21];
    const float* b_att     = (const float*)d_in[22];

    // workspace layout (floats)
    float* ws   = (float*)d_ws;
    float* sE   = ws;                                   // B*D
    float* tE   = sE   + (size_t)BN * DN;               // B*D
    float* negS = tE   + (size_t)BN * DN;               // B*NEG*D
    float* negT = negS + (size_t)BN * NEGN * DN;        // B*NEG*D
    float* posW = negT + (size_t)BN * NEGN * DN;        // 2*E*B
    float* heteW= posW + (size_t)2 * EN * BN;           // 2*E*B
    float* negW = heteW+ (size_t)2 * EN * BN;           // 2*E*B*NEG
    float* parts= negW + (size_t)2 * EN * BN * NEGN;    // B
    int*   apos = (int*)(parts + BN);                   // 8 ints
    bf16_t* WnT = (bf16_t*)(apos + 8);                  // 128*128 bf16 (32KB)

    prep_kernel<<<(DN * DN + 255) / 256, 256, 0, stream>>>(W_nbr, WnT);

    latent_kernel<<<(2 * BN + 2 * BN * NEGN) / 8, 128, 0, stream>>>(
        emb, W_node, b_node, s_ids, t_ids, s_negs, t_negs, sE, tE, negS, negT);

    edge_kernel<<<2 * BN, 256, 0, stream>>>(
        emb, ete, WnT, b_nbr, W_att, b_att,
        s_nbr_ids, s_nbr_msk, s_nbr_w,
        t_nbr_ids, t_nbr_msk, t_nbr_w,
        sE, tE, negS, negT, posW, heteW, negW);

    allpos_kernel<<<8, 256, 0, stream>>>(s_flags, t_flags, apos);

    loss_kernel<<<BN, 64, 0, stream>>>(
        e_types, ete, s_flags, t_flags, sE, tE, negS, negT,
        posW, heteW, negW, apos, parts);

    final_kernel<<<1, 256, 0, stream>>>(parts, ete, (float*)d_out);
}

// Round 5
// 202.203 us; speedup vs baseline: 1.2648x; 1.2648x over previous
//
#include <hip/hip_runtime.h>
#include <hip/hip_bf16.h>
#include <cstddef>

// Problem constants (must match reference)
#define BN   1024   // B
#define NEGN 5      // NEG
#define NBRN 50     // NBR
#define DN   128    // D
#define EN   4      // E
#define MPAD 64     // padded neighbor-row count for MFMA tiles
#define NEG_INF_F (-4294967295.0f)

typedef __bf16 bf16_t;
typedef __bf16 bf16x8 __attribute__((ext_vector_type(8)));
typedef __bf16 bf16x4 __attribute__((ext_vector_type(4)));
typedef float  f32x4  __attribute__((ext_vector_type(4)));

__device__ __forceinline__ float leaky_f(float x) { return x >= 0.0f ? x : 0.01f * x; }

__device__ __forceinline__ float wave_sum(float v) {
#pragma unroll
    for (int off = 32; off; off >>= 1) v += __shfl_xor(v, off, 64);
    return v;
}
__device__ __forceinline__ float wave_max(float v) {
#pragma unroll
    for (int off = 32; off; off >>= 1) v = fmaxf(v, __shfl_xor(v, off, 64));
    return v;
}
__device__ __forceinline__ float sigmoid_f(float x) {
    if (x >= 0.0f) { float z = __expf(-x); return 1.0f / (1.0f + z); }
    float z = __expf(x); return z / (1.0f + z);
}

// ---------------------------------------------------------------------------
// Kernel 0: prep — WnT_bf16[n][k] = bf16(W_nbr[k][n])
// ---------------------------------------------------------------------------
__global__ __launch_bounds__(256) void prep_kernel(
    const float* __restrict__ Wn, bf16_t* __restrict__ WnT)
{
    const int idx = blockIdx.x * 256 + threadIdx.x;
    if (idx < DN * DN) {
        const int n = idx >> 7, k = idx & 127;
        WnT[idx] = (bf16_t)Wn[k * DN + n];
    }
}

// ---------------------------------------------------------------------------
// Kernel 1: node latents  leaky(emb[id] @ W_node + b_node)  (fp32)
// ---------------------------------------------------------------------------
__global__ __launch_bounds__(128) void latent_kernel(
    const float* __restrict__ emb, const float* __restrict__ W, const float* __restrict__ bias,
    const int* __restrict__ s_ids, const int* __restrict__ t_ids,
    const int* __restrict__ s_negs, const int* __restrict__ t_negs,
    float* __restrict__ sE, float* __restrict__ tE,
    float* __restrict__ negS, float* __restrict__ negT)
{
    const int tid = threadIdx.x;           // 0..127 = output col
    const int r0 = blockIdx.x * 8;
    __shared__ float rows[8][DN];
    __shared__ int ids_l[8];

    if (tid < 8) {
        int r = r0 + tid;
        int id;
        if (r < BN)                       id = s_ids[r];
        else if (r < 2 * BN)              id = t_ids[r - BN];
        else if (r < 2 * BN + BN * NEGN)  id = s_negs[r - 2 * BN];
        else                              id = t_negs[r - 2 * BN - BN * NEGN];
        ids_l[tid] = id;
    }
    __syncthreads();
#pragma unroll
    for (int r8 = 0; r8 < 8; ++r8)
        rows[r8][tid] = emb[(size_t)ids_l[r8] * DN + tid];
    __syncthreads();

    float acc[8];
#pragma unroll
    for (int r8 = 0; r8 < 8; ++r8) acc[r8] = 0.0f;

    for (int i0 = 0; i0 < DN; i0 += 4) {
        const float w0 = W[(i0 + 0) * DN + tid];
        const float w1 = W[(i0 + 1) * DN + tid];
        const float w2 = W[(i0 + 2) * DN + tid];
        const float w3 = W[(i0 + 3) * DN + tid];
#pragma unroll
        for (int r8 = 0; r8 < 8; ++r8) {
            const float4 a = *reinterpret_cast<const float4*>(&rows[r8][i0]);
            acc[r8] = fmaf(a.x, w0, fmaf(a.y, w1, fmaf(a.z, w2, fmaf(a.w, w3, acc[r8]))));
        }
    }
    const float bb = bias[tid];
#pragma unroll
    for (int r8 = 0; r8 < 8; ++r8) {
        const int r = r0 + r8;
        const float v = leaky_f(acc[r8] + bb);
        float* dst;
        if (r < BN)                       dst = sE   + (size_t)r * DN;
        else if (r < 2 * BN)              dst = tE   + (size_t)(r - BN) * DN;
        else if (r < 2 * BN + BN * NEGN)  dst = negS + (size_t)(r - 2 * BN) * DN;
        else                              dst = negT + (size_t)(r - 2 * BN - BN * NEGN) * DN;
        dst[tid] = v;
    }
}

// ---------------------------------------------------------------------------
// Kernel 2: per (side,e,b) edge block — MFMA + T14 issue-early staging.
//   (1) issue 50-row gather into regs (direct global id reads, no barrier)
//   (2) VT rows (npe,tgt,neg0..4,Wa) + exact fp32 norms under gather latency
//   (3) write staged regs -> LDS bf16 swizzled; single barrier
//   (4) GEMM1 MFMA (L=leaky(Eg@Wn+bn), B from global WnT), epilogue n2+L->LDS
//   (5) GEMM2 MFMA (dots = L @ VT^T, cols 0..7), barrier
//   (6) single-wave softmax/pos/neg/hete
// grid = 2*E*B = 8192 blocks x 256 thr. LDS ~22.5KB; target 6 blocks/CU.
// ---------------------------------------------------------------------------
__global__ __launch_bounds__(256, 6) void edge_kernel(
    const float* __restrict__ emb, const float* __restrict__ ete,
    const bf16_t* __restrict__ WnT, const float* __restrict__ bn,
    const float* __restrict__ Wa, const float* __restrict__ ba,
    const int* __restrict__ s_nbr_ids, const int* __restrict__ s_nbr_masks, const float* __restrict__ s_nbr_w,
    const int* __restrict__ t_nbr_ids, const int* __restrict__ t_nbr_masks, const float* __restrict__ t_nbr_w,
    const float* __restrict__ sE, const float* __restrict__ tE,
    const float* __restrict__ negS, const float* __restrict__ negT,
    float* __restrict__ posW, float* __restrict__ heteW, float* __restrict__ negW)
{
    const int bid  = blockIdx.x;
    const int b    = bid & (BN - 1);
    const int e    = (bid >> 10) & 3;
    const int side = bid >> 12;

    const int*   ids_p;  const int* mask_p; const float* w_p;
    const float* node_p; const float* tgt_p; const float* negs_p;
    if (side == 0) { ids_p = s_nbr_ids; mask_p = s_nbr_masks; w_p = s_nbr_w;
                     node_p = sE; tgt_p = tE; negs_p = negT; }
    else           { ids_p = t_nbr_ids; mask_p = t_nbr_masks; w_p = t_nbr_w;
                     node_p = tE; tgt_p = sE; negs_p = negS; }
    const int base = (e * BN + b) * NBRN;

    // LDS (~22.5 KB): swizzle = element-index XOR (col ^ ((row&7)<<3)) per row
    __shared__ __align__(16) bf16_t buf[MPAD * DN];  // 16 KB: Eg rows -> L (in place)
    __shared__ __align__(16) bf16_t VT[16 * DN];     // 4 KB: rows 0..7 data, 8..15 zero
    __shared__ float dotL[MPAD][9];                  // 2.25 KB (cols 0..7)
    __shared__ float n2_l[MPAD];
    __shared__ float norm_l[8];

    const int tid  = threadIdx.x;
    const int lane = tid & 63;
    const int w    = tid >> 6;       // wave id 0..3
    const int l15  = lane & 15;
    const int l4   = lane >> 4;

    // ---- (1) issue gather into registers: flat slot = j*32 + c4 ----
    float4 rg[7];
#pragma unroll
    for (int i = 0; i < 7; ++i) {
        const int flat = i * 256 + tid;
        if (flat < NBRN * 32) {
            const int j = flat >> 5, c4 = flat & 31;
            const int id = ids_p[base + j];          // L1-broadcast (2 lines)
            rg[i] = *reinterpret_cast<const float4*>(emb + (size_t)id * DN + c4 * 4);
        }
    }

    // ---- (2) VT rows 0..7 + norms (exact fp32); runs under gather latency ----
    {
        const int q = tid >> 5, c4 = tid & 31;       // q 0..7
        const int c = c4 * 4;
        float4 v;
        if (q == 0) {
            const float4 np = *reinterpret_cast<const float4*>(node_p + (size_t)b * DN + c);
            const float4 ep = *reinterpret_cast<const float4*>(ete + e * DN + c);
            v.x = np.x + ep.x; v.y = np.y + ep.y; v.z = np.z + ep.z; v.w = np.w + ep.w;
        } else if (q == 1) {
            v = *reinterpret_cast<const float4*>(tgt_p + (size_t)b * DN + c);
        } else if (q < 7) {
            v = *reinterpret_cast<const float4*>(negs_p + ((size_t)b * NEGN + (q - 2)) * DN + c);
        } else {
            v = *reinterpret_cast<const float4*>(Wa + c);
        }
        float p = v.x * v.x + v.y * v.y + v.z * v.z + v.w * v.w;
#pragma unroll
        for (int off = 1; off <= 16; off <<= 1) p += __shfl_xor(p, off, 64);
        if (c4 == 0) norm_l[q] = p;
        bf16x4 h; h[0]=(bf16_t)v.x; h[1]=(bf16_t)v.y; h[2]=(bf16_t)v.z; h[3]=(bf16_t)v.w;
        *reinterpret_cast<bf16x4*>(&VT[q * DN + (c ^ ((q & 7) << 3))]) = h;
        // zero rows 8..15 (B-frag safety for lanes l15>=8)
        const int qz = 8 + q;
        bf16x4 z; z[0]=(bf16_t)0.f; z[1]=(bf16_t)0.f; z[2]=(bf16_t)0.f; z[3]=(bf16_t)0.f;
        *reinterpret_cast<bf16x4*>(&VT[qz * DN + (c ^ ((qz & 7) << 3))]) = z;
    }

    // ---- (3) write staged rows; zero-pad rows 50..63; one barrier ----
#pragma unroll
    for (int i = 0; i < 7; ++i) {
        const int flat = i * 256 + tid;
        if (flat < NBRN * 32) {
            const int j = flat >> 5, c4 = flat & 31;
            bf16x4 h; h[0]=(bf16_t)rg[i].x; h[1]=(bf16_t)rg[i].y;
                      h[2]=(bf16_t)rg[i].z; h[3]=(bf16_t)rg[i].w;
            *reinterpret_cast<bf16x4*>(&buf[j * DN + ((c4 * 4) ^ ((j & 7) << 3))]) = h;
        }
    }
    for (int idx = tid; idx < (MPAD - NBRN) * 32; idx += 256) {
        const int j = NBRN + (idx >> 5), c4 = idx & 31;
        bf16x4 z; z[0]=(bf16_t)0.f; z[1]=(bf16_t)0.f; z[2]=(bf16_t)0.f; z[3]=(bf16_t)0.f;
        *reinterpret_cast<bf16x4*>(&buf[j * DN + ((c4 * 4) ^ ((j & 7) << 3))]) = z;
    }
    __syncthreads();

    // ---- (4) GEMM1: L = leaky(Eg @ Wn + bn); B-frags from global WnT ----
    f32x4 accv[8];
#pragma unroll
    for (int nt = 0; nt < 8; ++nt) accv[nt] = (f32x4){0.f, 0.f, 0.f, 0.f};

    const int arow = w * 16 + l15;
#pragma unroll 1
    for (int ks = 0; ks < 4; ++ks) {
        const int k0 = ks * 32 + l4 * 8;
        const bf16x8 a = *reinterpret_cast<const bf16x8*>(
            &buf[arow * DN + (k0 ^ ((arow & 7) << 3))]);
#pragma unroll
        for (int nt = 0; nt < 8; ++nt) {
            const bf16x8 bfr = *reinterpret_cast<const bf16x8*>(
                WnT + (nt * 16 + l15) * DN + k0);
            accv[nt] = __builtin_amdgcn_mfma_f32_16x16x32_bf16(a, bfr, accv[nt], 0, 0, 0);
        }
    }

    // epilogue: bias+leaky, ||L_j||^2, store L into own rows of buf
    float n2p[4] = {0.f, 0.f, 0.f, 0.f};
#pragma unroll
    for (int nt = 0; nt < 8; ++nt) {
        const int coln = nt * 16 + l15;
        const float bb = bn[coln];
#pragma unroll
        for (int r = 0; r < 4; ++r) {
            float v = leaky_f(accv[nt][r] + bb);
            n2p[r] += v * v;
            const int row = w * 16 + l4 * 4 + r;
            buf[row * DN + (coln ^ ((row & 7) << 3))] = (bf16_t)v;
        }
    }
#pragma unroll
    for (int r = 0; r < 4; ++r) {
        float p = n2p[r];
#pragma unroll
        for (int off = 1; off <= 8; off <<= 1) p += __shfl_xor(p, off, 64);
        if (l15 == 0) n2_l[w * 16 + l4 * 4 + r] = p;
    }

    // ---- (5) GEMM2: dots = L @ VT^T (cols 0..7 useful; own rows only) ----
    f32x4 dacc = (f32x4){0.f, 0.f, 0.f, 0.f};
#pragma unroll
    for (int ks = 0; ks < 4; ++ks) {
        const int k0 = ks * 32 + l4 * 8;
        const bf16x8 a   = *reinterpret_cast<const bf16x8*>(
            &buf[arow * DN + (k0 ^ ((arow & 7) << 3))]);
        const bf16x8 bfr = *reinterpret_cast<const bf16x8*>(
            &VT[l15 * DN + (k0 ^ ((l15 & 7) << 3))]);
        dacc = __builtin_amdgcn_mfma_f32_16x16x32_bf16(a, bfr, dacc, 0, 0, 0);
    }
    if (l15 < 8) {
#pragma unroll
        for (int r = 0; r < 4; ++r)
            dotL[w * 16 + l4 * 4 + r][l15] = dacc[r];
    }
    __syncthreads();

    // ---- (6) softmax + pos/neg/hete: single wave, lane j = neighbor j ----
    if (tid < 64) {
        const int j = tid;
        const bool act = j < NBRN;
        float mut = 0.0f, wj = 0.0f, hw = 0.0f;
        float mn[NEGN];
#pragma unroll
        for (int n = 0; n < NEGN; ++n) mn[n] = 0.0f;
        int mk = 0;
        float x = NEG_INF_F;
        if (act) {
            const float n2 = n2_l[j];
            const float dj = 2.0f * dotL[j][0] - norm_l[0] - n2;
            mut            = 2.0f * dotL[j][1] - norm_l[1] - n2;
#pragma unroll
            for (int n = 0; n < NEGN; ++n) mn[n] = 2.0f * dotL[j][2 + n] - norm_l[2 + n] - n2;
            hw = dotL[j][7];
            mk = mask_p[base + j];
            wj = w_p[base + j];
            x = mk ? dj : NEG_INF_F;
        }
        const float m  = wave_max(x);
        const float ex = act ? __expf(x - m) : 0.0f;   // exactly 50 summands
        const float S  = wave_sum(ex);
        const float atts  = ex / S;
        const float atts2 = (act && mk) ? atts : 0.0f;
        const float nw = atts2 * wj;
        const float posv = wave_sum(nw * mut);
        float nsum[NEGN];
#pragma unroll
        for (int n = 0; n < NEGN; ++n) nsum[n] = wave_sum(nw * mn[n]);
        const float wsum = wave_sum(act ? wj : 0.0f);
        const float msum = wave_sum(act ? (float)mk : 0.0f);
        const float hsum = wave_sum(atts2 * hw);       // = avg_embed . Wa
        if (tid == 0) {
            const float nbr_n = fminf(fmaxf(msum, 1.0f), (float)NBRN);
            const float ave_w = wsum / nbr_n;
            const int o = (side * EN + e) * BN + b;
            posW[o]  = posv;
            heteW[o] = leaky_f(ave_w * hsum + ba[0]);
#pragma unroll
            for (int n = 0; n < NEGN; ++n) negW[(size_t)o * NEGN + n] = nsum[n];
        }
    }
}

// ---------------------------------------------------------------------------
// Kernel 3: allpos[side][e] = all_b(flags[e][b] > 0)
// ---------------------------------------------------------------------------
__global__ __launch_bounds__(256) void allpos_kernel(
    const int* __restrict__ s_flags, const int* __restrict__ t_flags, int* __restrict__ allpos)
{
    const int side = blockIdx.x >> 2, e = blockIdx.x & 3;
    const int* f = side ? t_flags : s_flags;
    int ok = 1;
    for (int b = threadIdx.x; b < BN; b += 256) ok &= (f[e * BN + b] > 0);
    ok = __syncthreads_and(ok);
    if (threadIdx.x == 0) allpos[blockIdx.x] = ok;
}

// ---------------------------------------------------------------------------
// Kernel 4: per-b loss partial (mu, neg_mus, double-softmax over E, log-sigmoids)
// ---------------------------------------------------------------------------
__global__ __launch_bounds__(64) void loss_kernel(
    const int* __restrict__ e_types, const float* __restrict__ ete,
    const int* __restrict__ s_flags, const int* __restrict__ t_flags,
    const float* __restrict__ sE, const float* __restrict__ tE,
    const float* __restrict__ negS, const float* __restrict__ negT,
    const float* __restrict__ posW, const float* __restrict__ heteW,
    const float* __restrict__ negW, const int* __restrict__ allpos,
    float* __restrict__ partials)
{
    const int b = blockIdx.x;
    const int lane = threadIdx.x;   // 64 lanes, each covers dims lane and lane+64
    const int et = e_types[b];

    const float se0 = sE[(size_t)b * DN + lane],      se1 = sE[(size_t)b * DN + lane + 64];
    const float te0 = tE[(size_t)b * DN + lane],      te1 = tE[(size_t)b * DN + lane + 64];
    const float ee0 = ete[et * DN + lane],            ee1 = ete[et * DN + lane + 64];

    float d0 = se0 + ee0 - te0, d1 = se1 + ee1 - te1;
    const float mu = -wave_sum(d0 * d0 + d1 * d1);

    float nmst[NEGN], nmts[NEGN];
#pragma unroll
    for (int n = 0; n < NEGN; ++n) {
        const float* nt = negT + ((size_t)b * NEGN + n) * DN;
        const float* ns = negS + ((size_t)b * NEGN + n) * DN;
        float a0 = se0 - nt[lane], a1 = se1 - nt[lane + 64];
        nmst[n] = -wave_sum(a0 * a0 + a1 * a1);
        float c0 = te0 - ns[lane], c1 = te1 - ns[lane + 64];
        nmts[n] = -wave_sum(c0 * c0 + c1 * c1);
    }

    if (lane == 0) {
        float posl[2];
        float negl[2][NEGN];
        for (int side = 0; side < 2; ++side) {
            const int* fl = side ? t_flags : s_flags;
            float att[EN], pv[EN];
            int mk[EN], ap[EN];
#pragma unroll
            for (int ei = 0; ei < EN; ++ei) {
                ap[ei] = allpos[side * EN + ei];
                mk[ei] = fl[ei * BN + b] > 0;
                const int o = (side * EN + ei) * BN + b;
                att[ei] = ap[ei] ? 0.0f : heteW[o];
                pv[ei]  = ap[ei] ? 0.0f : posW[o];
            }
            // softmax 1: where(mask, att, NEG_INF)
            float x[EN], m = NEG_INF_F;
#pragma unroll
            for (int ei = 0; ei < EN; ++ei) { x[ei] = mk[ei] ? att[ei] : NEG_INF_F; m = fmaxf(m, x[ei]); }
            float s = 0.0f, ex[EN];
#pragma unroll
            for (int ei = 0; ei < EN; ++ei) { ex[ei] = __expf(x[ei] - m); s += ex[ei]; }
            float v1[EN];
#pragma unroll
            for (int ei = 0; ei < EN; ++ei) v1[ei] = ex[ei] / s;
            // softmax 2: softmax(where(mask, v1, 0.0))  (no output masking!)
            float y[EN], m2 = NEG_INF_F;
#pragma unroll
            for (int ei = 0; ei < EN; ++ei) { y[ei] = mk[ei] ? v1[ei] : 0.0f; m2 = fmaxf(m2, y[ei]); }
            float s2 = 0.0f, ex2[EN];
#pragma unroll
            for (int ei = 0; ei < EN; ++ei) { ex2[ei] = __expf(y[ei] - m2); s2 += ex2[ei]; }
            float pl = 0.0f;
            float nl[NEGN];
#pragma unroll
            for (int n = 0; n < NEGN; ++n) nl[n] = 0.0f;
#pragma unroll
            for (int ei = 0; ei < EN; ++ei) {
                const float na = ex2[ei] / s2;
                pl += na * pv[ei];
                const int o = (side * EN + ei) * BN + b;
#pragma unroll
                for (int n = 0; n < NEGN; ++n) {
                    const float nv = ap[ei] ? 0.0f : negW[(size_t)o * NEGN + n];
                    nl[n] += na * nv;
                }
            }
            posl[side] = pl;
#pragma unroll
            for (int n = 0; n < NEGN; ++n) negl[side][n] = nl[n];
        }

        const float lam = mu + posl[0] + posl[1];
        float total = -logf(sigmoid_f(lam) + 1e-6f) / (float)BN;
#pragma unroll
        for (int n = 0; n < NEGN; ++n) {
            total += -logf(sigmoid_f(-(nmst[n] + negl[0][n])) + 1e-6f) / (float)(BN * NEGN);
            total += -logf(sigmoid_f(-(nmts[n] + negl[1][n])) + 1e-6f) / (float)(BN * NEGN);
        }
        partials[b] = total;
    }
}

// ---------------------------------------------------------------------------
// Kernel 5: reduce partials + NORM_RATE * sum(ete^2) -> d_out[0]
// ---------------------------------------------------------------------------
__global__ __launch_bounds__(256) void final_kernel(
    const float* __restrict__ partials, const float* __restrict__ ete, float* __restrict__ out)
{
    __shared__ float red[256];
    const int tid = threadIdx.x;
    float s = 0.0f;
    for (int i = tid; i < BN; i += 256) s += partials[i];
    float t = 0.0f;
    for (int i = tid; i < EN * DN; i += 256) { const float v = ete[i]; t += v * v; }
    red[tid] = s + 1e-4f * t;
    __syncthreads();
    for (int st = 128; st > 0; st >>= 1) {
        if (tid < st) red[tid] += red[tid + st];
        __syncthreads();
    }
    if (tid == 0) out[0] = red[0];
}

// ---------------------------------------------------------------------------
extern "C" void kernel_launch(void* const* d_in, const int* in_sizes, int n_in,
                              void* d_out, int out_size, void* d_ws, size_t ws_size,
                              hipStream_t stream)
{
    const int*   e_types   = (const int*)  d_in[0];
    const int*   s_ids     = (const int*)  d_in[1];
    // d_in[2] s_types: inert
    const int*   s_negs    = (const int*)  d_in[3];
    const int*   s_nbr_ids = (const int*)  d_in[4];
    const int*   s_nbr_msk = (const int*)  d_in[5];
    const float* s_nbr_w   = (const float*)d_in[6];
    const int*   s_flags   = (const int*)  d_in[7];
    const int*   t_ids     = (const int*)  d_in[8];
    // d_in[9] t_types: inert
    const int*   t_negs    = (const int*)  d_in[10];
    const int*   t_nbr_ids = (const int*)  d_in[11];
    const int*   t_nbr_msk = (const int*)  d_in[12];
    const float* t_nbr_w   = (const float*)d_in[13];
    const int*   t_flags   = (const int*)  d_in[14];
    const float* emb       = (const float*)d_in[15];
    const float* ete       = (const float*)d_in[16];
    const float* W_node    = (const float*)d_in[17];
    const float* b_node    = (const float*)d_in[18];
    const float* W_nbr     = (const float*)d_in[19];
    const float* b_nbr     = (const float*)d_in[20];
    const float* W_att     = (const float*)d_in[21];
    const float* b_att     = (const float*)d_in[22];

    // workspace layout (floats)
    float* ws   = (float*)d_ws;
    float* sE   = ws;                                   // B*D
    float* tE   = sE   + (size_t)BN * DN;               // B*D
    float* negS = tE   + (size_t)BN * DN;               // B*NEG*D
    float* negT = negS + (size_t)BN * NEGN * DN;        // B*NEG*D
    float* posW = negT + (size_t)BN * NEGN * DN;        // 2*E*B
    float* heteW= posW + (size_t)2 * EN * BN;           // 2*E*B
    float* negW = heteW+ (size_t)2 * EN * BN;           // 2*E*B*NEG
    float* parts= negW + (size_t)2 * EN * BN * NEGN;    // B
    int*   apos = (int*)(parts + BN);                   // 8 ints
    bf16_t* WnT = (bf16_t*)(apos + 8);                  // 128*128 bf16 (32KB)

    prep_kernel<<<(DN * DN + 255) / 256, 256, 0, stream>>>(W_nbr, WnT);

    latent_kernel<<<(2 * BN + 2 * BN * NEGN) / 8, 128, 0, stream>>>(
        emb, W_node, b_node, s_ids, t_ids, s_negs, t_negs, sE, tE, negS, negT);

    edge_kernel<<<2 * EN * BN, 256, 0, stream>>>(
        emb, ete, WnT, b_nbr, W_att, b_att,
        s_nbr_ids, s_nbr_msk, s_nbr_w,
        t_nbr_ids, t_nbr_msk, t_nbr_w,
        sE, tE, negS, negT, posW, heteW, negW);

    allpos_kernel<<<8, 256, 0, stream>>>(s_flags, t_flags, apos);

    loss_kernel<<<BN, 64, 0, stream>>>(
        e_types, ete, s_flags, t_flags, sE, tE, negS, negT,
        posW, heteW, negW, apos, parts);

    final_kernel<<<1, 256, 0, stream>>>(parts, ete, (float*)d_out);
}

// Round 6
// 123.489 us; speedup vs baseline: 2.0710x; 1.6374x over previous
//
#include <hip/hip_runtime.h>
#include <hip/hip_bf16.h>
#include <cstddef>

// Problem constants (must match reference)
#define BN   1024   // B
#define NEGN 5      // NEG
#define NBRN 50     // NBR
#define DN   128    // D
#define EN   4      // E
#define MPAD 64     // padded neighbor-row count for MFMA tiles
#define NEG_INF_F (-4294967295.0f)

typedef __bf16 bf16_t;
typedef __bf16 bf16x8 __attribute__((ext_vector_type(8)));
typedef __bf16 bf16x4 __attribute__((ext_vector_type(4)));
typedef float  f32x4  __attribute__((ext_vector_type(4)));

__device__ __forceinline__ float leaky_f(float x) { return x >= 0.0f ? x : 0.01f * x; }

__device__ __forceinline__ float wave_sum(float v) {
#pragma unroll
    for (int off = 32; off; off >>= 1) v += __shfl_xor(v, off, 64);
    return v;
}
__device__ __forceinline__ float wave_max(float v) {
#pragma unroll
    for (int off = 32; off; off >>= 1) v = fmaxf(v, __shfl_xor(v, off, 64));
    return v;
}
__device__ __forceinline__ float sigmoid_f(float x) {
    if (x >= 0.0f) { float z = __expf(-x); return 1.0f / (1.0f + z); }
    float z = __expf(x); return z / (1.0f + z);
}

// ---------------------------------------------------------------------------
// Kernel 0: prep — WnT_bf16[n][k] = bf16(W_nbr[k][n])
// ---------------------------------------------------------------------------
__global__ __launch_bounds__(256) void prep_kernel(
    const float* __restrict__ Wn, bf16_t* __restrict__ WnT)
{
    const int idx = blockIdx.x * 256 + threadIdx.x;
    if (idx < DN * DN) {
        const int n = idx >> 7, k = idx & 127;
        WnT[idx] = (bf16_t)Wn[k * DN + n];
    }
}

// ---------------------------------------------------------------------------
// Kernel 1: node latents  leaky(emb[id] @ W_node + b_node)  (fp32)
// ---------------------------------------------------------------------------
__global__ __launch_bounds__(128) void latent_kernel(
    const float* __restrict__ emb, const float* __restrict__ W, const float* __restrict__ bias,
    const int* __restrict__ s_ids, const int* __restrict__ t_ids,
    const int* __restrict__ s_negs, const int* __restrict__ t_negs,
    float* __restrict__ sE, float* __restrict__ tE,
    float* __restrict__ negS, float* __restrict__ negT)
{
    const int tid = threadIdx.x;           // 0..127 = output col
    const int r0 = blockIdx.x * 8;
    __shared__ float rows[8][DN];
    __shared__ int ids_l[8];

    if (tid < 8) {
        int r = r0 + tid;
        int id;
        if (r < BN)                       id = s_ids[r];
        else if (r < 2 * BN)              id = t_ids[r - BN];
        else if (r < 2 * BN + BN * NEGN)  id = s_negs[r - 2 * BN];
        else                              id = t_negs[r - 2 * BN - BN * NEGN];
        ids_l[tid] = id;
    }
    __syncthreads();
#pragma unroll
    for (int r8 = 0; r8 < 8; ++r8)
        rows[r8][tid] = emb[(size_t)ids_l[r8] * DN + tid];
    __syncthreads();

    float acc[8];
#pragma unroll
    for (int r8 = 0; r8 < 8; ++r8) acc[r8] = 0.0f;

    for (int i0 = 0; i0 < DN; i0 += 4) {
        const float w0 = W[(i0 + 0) * DN + tid];
        const float w1 = W[(i0 + 1) * DN + tid];
        const float w2 = W[(i0 + 2) * DN + tid];
        const float w3 = W[(i0 + 3) * DN + tid];
#pragma unroll
        for (int r8 = 0; r8 < 8; ++r8) {
            const float4 a = *reinterpret_cast<const float4*>(&rows[r8][i0]);
            acc[r8] = fmaf(a.x, w0, fmaf(a.y, w1, fmaf(a.z, w2, fmaf(a.w, w3, acc[r8]))));
        }
    }
    const float bb = bias[tid];
#pragma unroll
    for (int r8 = 0; r8 < 8; ++r8) {
        const int r = r0 + r8;
        const float v = leaky_f(acc[r8] + bb);
        float* dst;
        if (r < BN)                       dst = sE   + (size_t)r * DN;
        else if (r < 2 * BN)              dst = tE   + (size_t)(r - BN) * DN;
        else if (r < 2 * BN + BN * NEGN)  dst = negS + (size_t)(r - 2 * BN) * DN;
        else                              dst = negT + (size_t)(r - 2 * BN - BN * NEGN) * DN;
        dst[tid] = v;
    }
}

// ---------------------------------------------------------------------------
// Kernel 2: per (side,e,b) edge block — MFMA, col-split GEMM1 with B-reuse.
//   (1) gather 50 emb rows -> regs (issue-early)
//   (2) VT rows 0..7 + exact fp32 norms (under gather latency)
//   (3) staged regs -> LDS bf16 swizzled; barrier
//   (4) GEMM1 col-split: wave w owns cols 32w..32w+31 of ALL 64 rows;
//       8 B-frags loaded ONCE upfront (4x less WnT traffic), reused over
//       4 row-tiles. Epilogue: bias+leaky, per-row ||L||^2 partial (16-lane
//       reduce), L -> LDS. barrier
//   (5) GEMM2: wave w rows 16w..16w+15, dots = L @ VT^T. barrier
//   (6) single-wave softmax/pos/neg/hete (mask/weight prefetched at start)
// grid = 2*E*B = 8192 blocks x 256 thr. LDS ~23.3KB, VGPR-capped 4 blocks/CU.
// ---------------------------------------------------------------------------
__global__ __launch_bounds__(256, 4) void edge_kernel(
    const float* __restrict__ emb, const float* __restrict__ ete,
    const bf16_t* __restrict__ WnT, const float* __restrict__ bn,
    const float* __restrict__ Wa, const float* __restrict__ ba,
    const int* __restrict__ s_nbr_ids, const int* __restrict__ s_nbr_masks, const float* __restrict__ s_nbr_w,
    const int* __restrict__ t_nbr_ids, const int* __restrict__ t_nbr_masks, const float* __restrict__ t_nbr_w,
    const float* __restrict__ sE, const float* __restrict__ tE,
    const float* __restrict__ negS, const float* __restrict__ negT,
    float* __restrict__ posW, float* __restrict__ heteW, float* __restrict__ negW)
{
    const int bid  = blockIdx.x;
    const int b    = bid & (BN - 1);
    const int e    = (bid >> 10) & 3;
    const int side = bid >> 12;

    const int*   ids_p;  const int* mask_p; const float* w_p;
    const float* node_p; const float* tgt_p; const float* negs_p;
    if (side == 0) { ids_p = s_nbr_ids; mask_p = s_nbr_masks; w_p = s_nbr_w;
                     node_p = sE; tgt_p = tE; negs_p = negT; }
    else           { ids_p = t_nbr_ids; mask_p = t_nbr_masks; w_p = t_nbr_w;
                     node_p = tE; tgt_p = sE; negs_p = negS; }
    const int base = (e * BN + b) * NBRN;

    // LDS (~23.3 KB): swizzle = 8-elem slot index XOR (row&7) within each row
    __shared__ __align__(16) bf16_t buf[MPAD * DN];  // 16 KB: Eg rows -> L (in place)
    __shared__ __align__(16) bf16_t VT[16 * DN];     // 4 KB: rows 0..7 valid
    __shared__ float dotL[MPAD][9];                  // 2.25 KB (cols 0..7)
    __shared__ float n2p_l[4][MPAD];                 // 1 KB per-wave ||L||^2 partials
    __shared__ float norm_l[8];

    const int tid  = threadIdx.x;
    const int lane = tid & 63;
    const int w    = tid >> 6;       // wave id 0..3
    const int l15  = lane & 15;
    const int l4   = lane >> 4;

    // ---- (0) prefetch finale operands (used by wave 0 at the end) ----
    int   mk_r = 0; float wj_r = 0.0f;
    if (tid < NBRN) { mk_r = mask_p[base + tid]; wj_r = w_p[base + tid]; }

    // ---- (1) issue gather into registers: flat slot = j*32 + c4 ----
    float4 rg[7];
#pragma unroll
    for (int i = 0; i < 7; ++i) {
        const int flat = i * 256 + tid;
        if (flat < NBRN * 32) {
            const int j = flat >> 5, c4 = flat & 31;
            const int id = ids_p[base + j];          // L1-broadcast
            rg[i] = *reinterpret_cast<const float4*>(emb + (size_t)id * DN + c4 * 4);
        }
    }

    // ---- (2) VT rows 0..7 + norms (exact fp32); runs under gather latency ----
    {
        const int q = tid >> 5, c4 = tid & 31;       // q 0..7
        const int c = c4 * 4;
        float4 v;
        if (q == 0) {
            const float4 np = *reinterpret_cast<const float4*>(node_p + (size_t)b * DN + c);
            const float4 ep = *reinterpret_cast<const float4*>(ete + e * DN + c);
            v.x = np.x + ep.x; v.y = np.y + ep.y; v.z = np.z + ep.z; v.w = np.w + ep.w;
        } else if (q == 1) {
            v = *reinterpret_cast<const float4*>(tgt_p + (size_t)b * DN + c);
        } else if (q < 7) {
            v = *reinterpret_cast<const float4*>(negs_p + ((size_t)b * NEGN + (q - 2)) * DN + c);
        } else {
            v = *reinterpret_cast<const float4*>(Wa + c);
        }
        float p = v.x * v.x + v.y * v.y + v.z * v.z + v.w * v.w;
#pragma unroll
        for (int off = 1; off <= 16; off <<= 1) p += __shfl_xor(p, off, 64);
        if (c4 == 0) norm_l[q] = p;
        bf16x4 h; h[0]=(bf16_t)v.x; h[1]=(bf16_t)v.y; h[2]=(bf16_t)v.z; h[3]=(bf16_t)v.w;
        *reinterpret_cast<bf16x4*>(&VT[q * DN + (c ^ ((q & 7) << 3))]) = h;
        // VT rows 8..15 left uninitialized: they only feed dot cols 8..15,
        // which are never stored (l15<8 guard below).
    }

    // ---- (3) write staged rows (swizzled); rows 50..63 left as-is (unused
    //      outputs only); one barrier ----
#pragma unroll
    for (int i = 0; i < 7; ++i) {
        const int flat = i * 256 + tid;
        if (flat < NBRN * 32) {
            const int j = flat >> 5, c4 = flat & 31;
            bf16x4 h; h[0]=(bf16_t)rg[i].x; h[1]=(bf16_t)rg[i].y;
                      h[2]=(bf16_t)rg[i].z; h[3]=(bf16_t)rg[i].w;
            *reinterpret_cast<bf16x4*>(&buf[j * DN + ((c4 * 4) ^ ((j & 7) << 3))]) = h;
        }
    }
    __syncthreads();

    // ---- (4) GEMM1 col-split: 8 B-frags upfront, reused over 4 row-tiles ----
    bf16x8 bfr[2][4];
#pragma unroll
    for (int ct = 0; ct < 2; ++ct)
#pragma unroll
        for (int ks = 0; ks < 4; ++ks)
            bfr[ct][ks] = *reinterpret_cast<const bf16x8*>(
                WnT + ((2 * w + ct) * 16 + l15) * DN + ks * 32 + l4 * 8);

    f32x4 acc[4][2];
#pragma unroll
    for (int rt = 0; rt < 4; ++rt) {
        acc[rt][0] = (f32x4){0.f, 0.f, 0.f, 0.f};
        acc[rt][1] = (f32x4){0.f, 0.f, 0.f, 0.f};
    }
#pragma unroll
    for (int rt = 0; rt < 4; ++rt) {
        const int row = rt * 16 + l15;
        bf16x8 a[4];
#pragma unroll
        for (int ks = 0; ks < 4; ++ks) {
            const int k0 = ks * 32 + l4 * 8;
            a[ks] = *reinterpret_cast<const bf16x8*>(
                &buf[row * DN + (k0 ^ ((row & 7) << 3))]);
        }
#pragma unroll
        for (int ks = 0; ks < 4; ++ks) {
            acc[rt][0] = __builtin_amdgcn_mfma_f32_16x16x32_bf16(a[ks], bfr[0][ks], acc[rt][0], 0, 0, 0);
            acc[rt][1] = __builtin_amdgcn_mfma_f32_16x16x32_bf16(a[ks], bfr[1][ks], acc[rt][1], 0, 0, 0);
        }
    }

    // epilogue: bias+leaky, L -> LDS (own cols, all rows), per-row n2 partials
    {
        const float bb0 = bn[(2 * w + 0) * 16 + l15];
        const float bb1 = bn[(2 * w + 1) * 16 + l15];
        const int c0 = (2 * w + 0) * 16 + l15;
        const int c1 = (2 * w + 1) * 16 + l15;
#pragma unroll
        for (int rt = 0; rt < 4; ++rt) {
#pragma unroll
            for (int r = 0; r < 4; ++r) {
                const int row = rt * 16 + l4 * 4 + r;
                const float v0 = leaky_f(acc[rt][0][r] + bb0);
                const float v1 = leaky_f(acc[rt][1][r] + bb1);
                const int sw = (row & 7) << 3;
                buf[row * DN + (c0 ^ sw)] = (bf16_t)v0;
                buf[row * DN + (c1 ^ sw)] = (bf16_t)v1;
                float p = v0 * v0 + v1 * v1;
#pragma unroll
                for (int off = 1; off <= 8; off <<= 1) p += __shfl_xor(p, off, 64);
                if (l15 == 0) n2p_l[w][row] = p;
            }
        }
    }
    __syncthreads();   // L complete (cross-wave cols)

    // ---- (5) GEMM2: wave w rows 16w..16w+15, dots = L @ VT^T ----
    {
        f32x4 dacc = (f32x4){0.f, 0.f, 0.f, 0.f};
        const int row = w * 16 + l15;
#pragma unroll
        for (int ks = 0; ks < 4; ++ks) {
            const int k0 = ks * 32 + l4 * 8;
            const bf16x8 a   = *reinterpret_cast<const bf16x8*>(
                &buf[row * DN + (k0 ^ ((row & 7) << 3))]);
            const bf16x8 bfv = *reinterpret_cast<const bf16x8*>(
                &VT[l15 * DN + (k0 ^ ((l15 & 7) << 3))]);
            dacc = __builtin_amdgcn_mfma_f32_16x16x32_bf16(a, bfv, dacc, 0, 0, 0);
        }
        if (l15 < 8) {
#pragma unroll
            for (int r = 0; r < 4; ++r)
                dotL[w * 16 + l4 * 4 + r][l15] = dacc[r];
        }
    }
    __syncthreads();

    // ---- (6) softmax + pos/neg/hete: single wave, lane j = neighbor j ----
    if (tid < 64) {
        const int j = tid;
        const bool act = j < NBRN;
        float mut = 0.0f, hw = 0.0f;
        float mn[NEGN];
#pragma unroll
        for (int n = 0; n < NEGN; ++n) mn[n] = 0.0f;
        float x = NEG_INF_F;
        if (act) {
            const float n2 = n2p_l[0][j] + n2p_l[1][j] + n2p_l[2][j] + n2p_l[3][j];
            const float dj = 2.0f * dotL[j][0] - norm_l[0] - n2;
            mut            = 2.0f * dotL[j][1] - norm_l[1] - n2;
#pragma unroll
            for (int n = 0; n < NEGN; ++n) mn[n] = 2.0f * dotL[j][2 + n] - norm_l[2 + n] - n2;
            hw = dotL[j][7];
            x = mk_r ? dj : NEG_INF_F;
        }
        const float m  = wave_max(x);
        const float ex = act ? __expf(x - m) : 0.0f;   // exactly 50 summands
        const float S  = wave_sum(ex);
        const float atts  = ex / S;
        const float atts2 = (act && mk_r) ? atts : 0.0f;
        const float nw = atts2 * wj_r;
        const float posv = wave_sum(nw * mut);
        float nsum[NEGN];
#pragma unroll
        for (int n = 0; n < NEGN; ++n) nsum[n] = wave_sum(nw * mn[n]);
        const float wsum = wave_sum(act ? wj_r : 0.0f);
        const float msum = wave_sum(act ? (float)mk_r : 0.0f);
        const float hsum = wave_sum(atts2 * hw);       // = avg_embed . Wa
        if (tid == 0) {
            const float nbr_n = fminf(fmaxf(msum, 1.0f), (float)NBRN);
            const float ave_w = wsum / nbr_n;
            const int o = (side * EN + e) * BN + b;
            posW[o]  = posv;
            heteW[o] = leaky_f(ave_w * hsum + ba[0]);
#pragma unroll
            for (int n = 0; n < NEGN; ++n) negW[(size_t)o * NEGN + n] = nsum[n];
        }
    }
}

// ---------------------------------------------------------------------------
// Kernel 3: allpos[side][e] = all_b(flags[e][b] > 0)
// ---------------------------------------------------------------------------
__global__ __launch_bounds__(256) void allpos_kernel(
    const int* __restrict__ s_flags, const int* __restrict__ t_flags, int* __restrict__ allpos)
{
    const int side = blockIdx.x >> 2, e = blockIdx.x & 3;
    const int* f = side ? t_flags : s_flags;
    int ok = 1;
    for (int b = threadIdx.x; b < BN; b += 256) ok &= (f[e * BN + b] > 0);
    ok = __syncthreads_and(ok);
    if (threadIdx.x == 0) allpos[blockIdx.x] = ok;
}

// ---------------------------------------------------------------------------
// Kernel 4: per-b loss partial (mu, neg_mus, double-softmax over E, log-sigmoids)
// ---------------------------------------------------------------------------
__global__ __launch_bounds__(64) void loss_kernel(
    const int* __restrict__ e_types, const float* __restrict__ ete,
    const int* __restrict__ s_flags, const int* __restrict__ t_flags,
    const float* __restrict__ sE, const float* __restrict__ tE,
    const float* __restrict__ negS, const float* __restrict__ negT,
    const float* __restrict__ posW, const float* __restrict__ heteW,
    const float* __restrict__ negW, const int* __restrict__ allpos,
    float* __restrict__ partials)
{
    const int b = blockIdx.x;
    const int lane = threadIdx.x;   // 64 lanes, each covers dims lane and lane+64
    const int et = e_types[b];

    const float se0 = sE[(size_t)b * DN + lane],      se1 = sE[(size_t)b * DN + lane + 64];
    const float te0 = tE[(size_t)b * DN + lane],      te1 = tE[(size_t)b * DN + lane + 64];
    const float ee0 = ete[et * DN + lane],            ee1 = ete[et * DN + lane + 64];

    float d0 = se0 + ee0 - te0, d1 = se1 + ee1 - te1;
    const float mu = -wave_sum(d0 * d0 + d1 * d1);

    float nmst[NEGN], nmts[NEGN];
#pragma unroll
    for (int n = 0; n < NEGN; ++n) {
        const float* nt = negT + ((size_t)b * NEGN + n) * DN;
        const float* ns = negS + ((size_t)b * NEGN + n) * DN;
        float a0 = se0 - nt[lane], a1 = se1 - nt[lane + 64];
        nmst[n] = -wave_sum(a0 * a0 + a1 * a1);
        float c0 = te0 - ns[lane], c1 = te1 - ns[lane + 64];
        nmts[n] = -wave_sum(c0 * c0 + c1 * c1);
    }

    if (lane == 0) {
        float posl[2];
        float negl[2][NEGN];
        for (int side = 0; side < 2; ++side) {
            const int* fl = side ? t_flags : s_flags;
            float att[EN], pv[EN];
            int mk[EN], ap[EN];
#pragma unroll
            for (int ei = 0; ei < EN; ++ei) {
                ap[ei] = allpos[side * EN + ei];
                mk[ei] = fl[ei * BN + b] > 0;
                const int o = (side * EN + ei) * BN + b;
                att[ei] = ap[ei] ? 0.0f : heteW[o];
                pv[ei]  = ap[ei] ? 0.0f : posW[o];
            }
            // softmax 1: where(mask, att, NEG_INF)
            float x[EN], m = NEG_INF_F;
#pragma unroll
            for (int ei = 0; ei < EN; ++ei) { x[ei] = mk[ei] ? att[ei] : NEG_INF_F; m = fmaxf(m, x[ei]); }
            float s = 0.0f, ex[EN];
#pragma unroll
            for (int ei = 0; ei < EN; ++ei) { ex[ei] = __expf(x[ei] - m); s += ex[ei]; }
            float v1[EN];
#pragma unroll
            for (int ei = 0; ei < EN; ++ei) v1[ei] = ex[ei] / s;
            // softmax 2: softmax(where(mask, v1, 0.0))  (no output masking!)
            float y[EN], m2 = NEG_INF_F;
#pragma unroll
            for (int ei = 0; ei < EN; ++ei) { y[ei] = mk[ei] ? v1[ei] : 0.0f; m2 = fmaxf(m2, y[ei]); }
            float s2 = 0.0f, ex2[EN];
#pragma unroll
            for (int ei = 0; ei < EN; ++ei) { ex2[ei] = __expf(y[ei] - m2); s2 += ex2[ei]; }
            float pl = 0.0f;
            float nl[NEGN];
#pragma unroll
            for (int n = 0; n < NEGN; ++n) nl[n] = 0.0f;
#pragma unroll
            for (int ei = 0; ei < EN; ++ei) {
                const float na = ex2[ei] / s2;
                pl += na * pv[ei];
                const int o = (side * EN + ei) * BN + b;
#pragma unroll
                for (int n = 0; n < NEGN; ++n) {
                    const float nv = ap[ei] ? 0.0f : negW[(size_t)o * NEGN + n];
                    nl[n] += na * nv;
                }
            }
            posl[side] = pl;
#pragma unroll
            for (int n = 0; n < NEGN; ++n) negl[side][n] = nl[n];
        }

        const float lam = mu + posl[0] + posl[1];
        float total = -logf(sigmoid_f(lam) + 1e-6f) / (float)BN;
#pragma unroll
        for (int n = 0; n < NEGN; ++n) {
            total += -logf(sigmoid_f(-(nmst[n] + negl[0][n])) + 1e-6f) / (float)(BN * NEGN);
            total += -logf(sigmoid_f(-(nmts[n] + negl[1][n])) + 1e-6f) / (float)(BN * NEGN);
        }
        partials[b] = total;
    }
}

// ---------------------------------------------------------------------------
// Kernel 5: reduce partials + NORM_RATE * sum(ete^2) -> d_out[0]
// ---------------------------------------------------------------------------
__global__ __launch_bounds__(256) void final_kernel(
    const float* __restrict__ partials, const float* __restrict__ ete, float* __restrict__ out)
{
    __shared__ float red[256];
    const int tid = threadIdx.x;
    float s = 0.0f;
    for (int i = tid; i < BN; i += 256) s += partials[i];
    float t = 0.0f;
    for (int i = tid; i < EN * DN; i += 256) { const float v = ete[i]; t += v * v; }
    red[tid] = s + 1e-4f * t;
    __syncthreads();
    for (int st = 128; st > 0; st >>= 1) {
        if (tid < st) red[tid] += red[tid + st];
        __syncthreads();
    }
    if (tid == 0) out[0] = red[0];
}

// ---------------------------------------------------------------------------
extern "C" void kernel_launch(void* const* d_in, const int* in_sizes, int n_in,
                              void* d_out, int out_size, void* d_ws, size_t ws_size,
                              hipStream_t stream)
{
    const int*   e_types   = (const int*)  d_in[0];
    const int*   s_ids     = (const int*)  d_in[1];
    // d_in[2] s_types: inert
    const int*   s_negs    = (const int*)  d_in[3];
    const int*   s_nbr_ids = (const int*)  d_in[4];
    const int*   s_nbr_msk = (const int*)  d_in[5];
    const float* s_nbr_w   = (const float*)d_in[6];
    const int*   s_flags   = (const int*)  d_in[7];
    const int*   t_ids     = (const int*)  d_in[8];
    // d_in[9] t_types: inert
    const int*   t_negs    = (const int*)  d_in[10];
    const int*   t_nbr_ids = (const int*)  d_in[11];
    const int*   t_nbr_msk = (const int*)  d_in[12];
    const float* t_nbr_w   = (const float*)d_in[13];
    const int*   t_flags   = (const int*)  d_in[14];
    const float* emb       = (const float*)d_in[15];
    const float* ete       = (const float*)d_in[16];
    const float* W_node    = (const float*)d_in[17];
    const float* b_node    = (const float*)d_in[18];
    const float* W_nbr     = (const float*)d_in[19];
    const float* b_nbr     = (const float*)d_in[20];
    const float* W_att     = (const float*)d_in[21];
    const float* b_att     = (const float*)d_in[22];

    // workspace layout (floats)
    float* ws   = (float*)d_ws;
    float* sE   = ws;                                   // B*D
    float* tE   = sE   + (size_t)BN * DN;               // B*D
    float* negS = tE   + (size_t)BN * DN;               // B*NEG*D
    float* negT = negS + (size_t)BN * NEGN * DN;        // B*NEG*D
    float* posW = negT + (size_t)BN * NEGN * DN;        // 2*E*B
    float* heteW= posW + (size_t)2 * EN * BN;           // 2*E*B
    float* negW = heteW+ (size_t)2 * EN * BN;           // 2*E*B*NEG
    float* parts= negW + (size_t)2 * EN * BN * NEGN;    // B
    int*   apos = (int*)(parts + BN);                   // 8 ints
    bf16_t* WnT = (bf16_t*)(apos + 8);                  // 128*128 bf16 (32KB)

    prep_kernel<<<(DN * DN + 255) / 256, 256, 0, stream>>>(W_nbr, WnT);

    latent_kernel<<<(2 * BN + 2 * BN * NEGN) / 8, 128, 0, stream>>>(
        emb, W_node, b_node, s_ids, t_ids, s_negs, t_negs, sE, tE, negS, negT);

    edge_kernel<<<2 * EN * BN, 256, 0, stream>>>(
        emb, ete, WnT, b_nbr, W_att, b_att,
        s_nbr_ids, s_nbr_msk, s_nbr_w,
        t_nbr_ids, t_nbr_msk, t_nbr_w,
        sE, tE, negS, negT, posW, heteW, negW);

    allpos_kernel<<<8, 256, 0, stream>>>(s_flags, t_flags, apos);

    loss_kernel<<<BN, 64, 0, stream>>>(
        e_types, ete, s_flags, t_flags, sE, tE, negS, negT,
        posW, heteW, negW, apos, parts);

    final_kernel<<<1, 256, 0, stream>>>(parts, ete, (float*)d_out);
}